// Round 13
// baseline (806.359 us; speedup 1.0000x reference)
//
#include <hip/hip_runtime.h>
#include <hip/hip_bf16.h>

typedef unsigned short u16;
typedef unsigned int u32;
typedef __attribute__((ext_vector_type(8))) short s16x8;
typedef __attribute__((ext_vector_type(4))) float f32x4;

constexpr int CD    = 180;
constexpr int CP    = 192;              // K-padded channel count
constexpr int BATCH = 4;
constexpr int RES   = 128;
constexpr int LSZ   = RES * RES;        // 16384
constexpr int NHEAD = 6;
constexpr int DH    = 30;
constexpr int NTOK  = 64;
constexpr int NWIN  = 1024;
constexpr int MROWS = NWIN * NTOK;      // 65536
constexpr size_t S192 = (size_t)MROWS * CP;
constexpr size_t S180 = (size_t)MROWS * CD;
constexpr size_t XSZ  = (size_t)BATCH * CD * LSZ;

__device__ __forceinline__ float b2f(u16 u) { return __uint_as_float(((u32)u) << 16); }
__device__ __forceinline__ u16 f2b(float f) {
    __hip_bfloat16 h = __float2bfloat16(f);
    return *reinterpret_cast<u16*>(&h);
}
// fast GELU (tanh form); |err vs exact erf-GELU| <~1e-3
__device__ __forceinline__ float gelu_f(float x) {
    float y = 0.7978845608028654f * (x + 0.044715f * x * x * x);
    float t = __expf(-2.f * fabsf(y));
    float th = (1.f - t) / (1.f + t);
    th = copysignf(th, y);
    return 0.5f * x * (1.f + th);
}

// ---------------- merged weight prep: 8 fragment-major jobs in one launch
struct PrepArgs {
    const float *s0, *s1, *s2, *s3, *s4, *s5, *s6, *s7;
    u16* dst;   // base of contiguous dst region (wg_e)
};
__device__ __forceinline__ void do_frag(const float* __restrict__ src,
        u16* __restrict__ dst, int N, int K, int nks, int li) {
    int e = li & 7, lr = (li >> 3) & 15, lk = (li >> 7) & 3, rest = li >> 9;
    int ks = rest % nks, ct = rest / nks;
    int n = ct * 16 + lr, k = ks * 32 + lk * 8 + e;
    float v = (n < N && k < K) ? src[n * K + k] : 0.f;
    dst[li] = f2b(v);
}
// proj weights: K=384 split layout (oute cols 0-191 pad, outb 192-383 pad)
__device__ __forceinline__ void do_frag_proj(const float* __restrict__ src,
        u16* __restrict__ dst, int li) {
    int e = li & 7, lr = (li >> 3) & 15, lk = (li >> 7) & 3, rest = li >> 9;
    int ks = rest % 12, ct = rest / 12;
    int n = ct * 16 + lr, k = ks * 32 + lk * 8 + e;
    int khalf = k & 191;
    int ksrc = (k < 192) ? khalf : 180 + khalf;
    float v = (n < 180 && khalf < 180) ? src[n * 360 + ksrc] : 0.f;
    dst[li] = f2b(v);
}
__global__ __launch_bounds__(256) void prep_all(PrepArgs pa) {
    int bid = blockIdx.x, t = threadIdx.x;
    if (bid < 144)       do_frag(pa.s0, pa.dst,          180, 180,  6, (bid       ) * 256 + t);
    else if (bid < 288)  do_frag(pa.s1, pa.dst + 36864,  180, 180,  6, (bid - 144 ) * 256 + t);
    else if (bid < 576)  do_frag_proj(pa.s2, pa.dst + 73728,           (bid - 288 ) * 256 + t);
    else if (bid < 864)  do_frag_proj(pa.s3, pa.dst + 147456,          (bid - 576 ) * 256 + t);
    else if (bid < 1440) do_frag(pa.s4, pa.dst + 221184, 720, 180,  6, (bid - 864 ) * 256 + t);
    else if (bid < 2016) do_frag(pa.s5, pa.dst + 368640, 720, 180,  6, (bid - 1440) * 256 + t);
    else if (bid < 2592) do_frag(pa.s6, pa.dst + 516096, 180, 720, 24, (bid - 2016) * 256 + t);
    else                 do_frag(pa.s7, pa.dst + 663552, 180, 720, 24, (bid - 2592) * 256 + t);
}

// ---------------- merged qkv weight prep (e and b)
__global__ __launch_bounds__(256) void prep_wqkv2(
        const float* __restrict__ we, const float* __restrict__ be,
        const float* __restrict__ wb, const float* __restrict__ bb,
        u16* __restrict__ wp_base, float* __restrict__ bp_base) {
    int gi = blockIdx.x * 256 + threadIdx.x;
    int flag = gi >= 576 * 192;
    int i = flag ? gi - 576 * 192 : gi;
    if (i >= 576 * 192) return;
    const float* w = flag ? wb : we;
    const float* bsrc = flag ? bb : be;
    u16* wp = wp_base + (size_t)flag * (576 * 192);
    float* bp = bp_base + flag * 576;
    int e = i & 7, lr = (i >> 3) & 15, lk = (i >> 7) & 3, rest = i >> 9;
    int ks = rest % 6, rest2 = rest / 6;
    int ct = rest2 % 6, head = rest2 / 6;
    int rr = ct * 16 + lr;
    int sec = rr >> 5, dd = rr & 31;
    int srow = sec * 180 + head * 30 + dd;
    int k = ks * 32 + lk * 8 + e;
    float scale = (sec == 0) ? 0.18257418583505536f : 1.f;
    float v = (dd < 30 && k < 180) ? w[srow * 180 + k] * scale : 0.f;
    wp[i] = f2b(v);
    if (ks == 0 && lk == 0 && e == 0)
        bp[head * 96 + rr] = (dd < 30) ? bsrc[srow] * scale : 0.f;
}

// ---------------- merged LN1 + roll + window partition (e and b)
__global__ __launch_bounds__(256) void ln_win2(
    const float* __restrict__ e_f, const float* __restrict__ b_f,
    const float* __restrict__ g_e, const float* __restrict__ be_e,
    const float* __restrict__ g_b, const float* __restrict__ be_b,
    u16* __restrict__ dst_base) {
    __shared__ float tile[NTOK][CD + 1];
    int bid = blockIdx.x;
    int flag = bid >> 10;
    int widx = bid & 1023;
    const float* src = flag ? b_f : e_f;
    const float* gamma = flag ? g_b : g_e;
    const float* beta = flag ? be_b : be_e;
    u16* dst = dst_base + (size_t)flag * S192;
    int b = widx >> 8, wrem = widx & 255;
    int wh = wrem >> 4, ww = wrem & 15;
    int t = threadIdx.x;
    for (int i = t; i < NTOK * CD; i += 256) {
        int c = i >> 6, pos = i & 63;
        int sh = ((wh << 3) + (pos >> 3) + 4) & 127;
        int sw = ((ww << 3) + (pos & 7) + 4) & 127;
        tile[pos][c] = src[(((size_t)b * CD + c) << 14) + (sh << 7) + sw];
    }
    __syncthreads();
    int pos = t >> 2, sub = t & 3;
    float s = 0.f, ss = 0.f;
    for (int k = 0; k < 45; ++k) {
        float v = tile[pos][sub * 45 + k];
        s += v; ss += v * v;
    }
    s += __shfl_xor(s, 1); ss += __shfl_xor(ss, 1);
    s += __shfl_xor(s, 2); ss += __shfl_xor(ss, 2);
    float mean = s * (1.f / CD);
    float rstd = rsqrtf(ss * (1.f / CD) - mean * mean + 1e-5f);
    size_t obase = ((size_t)widx * NTOK + pos) * CP;
    for (int k = 0; k < 45; ++k) {
        int c = sub * 45 + k;
        dst[obase + c] = f2b((tile[pos][c] - mean) * rstd * gamma[c] + beta[c]);
    }
    if (sub == 3) {
        for (int k = 0; k < 12; ++k) dst[obase + CD + k] = 0;
    }
}

// ---------------- merged MFMA gate (e and b), no LDS: direct A-fragments
__global__ __launch_bounds__(256) void gate2(
    const u16* __restrict__ A_base, const u16* __restrict__ W_base,
    const float* __restrict__ bias_e, const float* __restrict__ bias_b,
    u16* __restrict__ sig_base) {
    int bid = blockIdx.x, t = threadIdx.x;
    int flag = bid >> 10;
    int rb = bid & 1023;
    const u16* A = A_base + (size_t)flag * S192;
    const u16* Wb = W_base + flag * 36864;
    const float* bias = flag ? bias_b : bias_e;
    u16* sig = sig_base + (size_t)flag * S192;
    int wave = t >> 6, lane = t & 63, lr = lane & 15, lk = lane >> 4;
    const u16* arow = A + ((size_t)rb * 64 + wave * 16 + lr) * CP;
    s16x8 a[6];
    #pragma unroll
    for (int ks = 0; ks < 6; ++ks)
        a[ks] = *(const s16x8*)&arow[ks * 32 + lk * 8];
    for (int ct = 0; ct < 12; ++ct) {
        f32x4 acc = {0.f, 0.f, 0.f, 0.f};
        #pragma unroll
        for (int ks = 0; ks < 6; ++ks) {
            s16x8 b = *(const s16x8*)&Wb[((size_t)(ct * 6 + ks) * 64 + lane) * 8];
            acc = __builtin_amdgcn_mfma_f32_16x16x32_bf16(a[ks], b, acc, 0, 0, 0);
        }
        int c = ct * 16 + lr;
        if (c < CD) {
            float bb = bias[c];
            #pragma unroll
            for (int j = 0; j < 4; ++j) {
                int rowm = rb * 64 + wave * 16 + lk * 4 + j;
                float v = acc[j] + bb;
                v = 1.f / (1.f + __expf(-v));
                sig[(size_t)rowm * CP + c] = f2b(v);
            }
        }
    }
}

// ---------------- merged MFMA attention (e and b)
__global__ __launch_bounds__(256) void attn2(
    const u16* __restrict__ ew_base, const u16* __restrict__ wq_base,
    const float* __restrict__ bq_base, const float* __restrict__ rpb,
    u16* __restrict__ out_base) {
    __shared__ __align__(16) char smem[28448];
    u16*   ews  = (u16*)smem;                 // 64*200*2 = 25600 B (staging, dies)
    u16*   Qs   = (u16*)smem;                 // 64*36*2  =  4608
    u16*   Ks   = (u16*)(smem + 4608);
    u16*   Vt   = (u16*)(smem + 9216);        // 32*72*2  =  4608
    u16*   Pb   = (u16*)(smem + 13824);       // 64*72*2  =  9216
    float* rpbs = (float*)(smem + 23040);     // 1350*4   =  5400

    int bid = blockIdx.x;
    int flag = bid >> 10;
    int widx = bid & 1023;
    const u16* ew = ew_base + (size_t)flag * S192;
    const u16* Wq = wq_base + (size_t)flag * (576 * 192);
    const float* Bq = bq_base + flag * 576;
    u16* outp = out_base + (size_t)flag * S180;

    int wrem = widx & 255;
    int wh = wrem >> 4, ww = wrem & 15;
    bool edge = (wh == 15) || (ww == 15);
    int t = threadIdx.x;
    size_t wbase = (size_t)widx * NTOK * CD;
    size_t wb192 = (size_t)widx * NTOK * CP;

    for (int i = t; i < 64 * 24; i += 256) {
        int row = i / 24, seg = i % 24;
        *(s16x8*)&ews[row * 200 + seg * 8] = *(const s16x8*)&ew[wb192 + (size_t)row * CP + seg * 8];
    }
    __syncthreads();

    int wave = t >> 6, lane = t & 63, lr = lane & 15, lk = lane >> 4;
    s16x8 a[6];
    #pragma unroll
    for (int ks = 0; ks < 6; ++ks)
        a[ks] = *(const s16x8*)&ews[(wave * 16 + lr) * 200 + ks * 32 + lk * 8];
    __syncthreads();   // all waves done reading ews; region reusable

    for (int i = t; i < 1350; i += 256) rpbs[i] = rpb[i];  // visible after next barrier

    for (int h = 0; h < NHEAD; ++h) {
        #pragma unroll
        for (int ct = 0; ct < 6; ++ct) {
            f32x4 acc = {0.f, 0.f, 0.f, 0.f};
            #pragma unroll
            for (int ks = 0; ks < 6; ++ks) {
                s16x8 b = *(const s16x8*)&Wq[(((size_t)(h * 6 + ct) * 6 + ks) * 64 + lane) * 8];
                acc = __builtin_amdgcn_mfma_f32_16x16x32_bf16(a[ks], b, acc, 0, 0, 0);
            }
            int sec = ct >> 1;
            int dd = ((ct & 1) << 4) + lr;
            float bb = Bq[h * 96 + ct * 16 + lr];
            #pragma unroll
            for (int j = 0; j < 4; ++j) {
                int tok = wave * 16 + lk * 4 + j;
                float v = acc[j] + bb;
                if (sec == 0)      Qs[tok * 36 + dd] = f2b(v);
                else if (sec == 1) Ks[tok * 36 + dd] = f2b(v);
                else               Vt[dd * 72 + tok] = f2b(v);
            }
        }
        __syncthreads();
        f32x4 sv[4];
        {
            s16x8 qa = *(const s16x8*)&Qs[(wave * 16 + lr) * 36 + lk * 8];
            #pragma unroll
            for (int ct = 0; ct < 4; ++ct) {
                s16x8 kb = *(const s16x8*)&Ks[(ct * 16 + lr) * 36 + lk * 8];
                f32x4 z = {0.f, 0.f, 0.f, 0.f};
                sv[ct] = __builtin_amdgcn_mfma_f32_16x16x32_bf16(qa, kb, z, 0, 0, 0);
            }
            #pragma unroll
            for (int ct = 0; ct < 4; ++ct) {
                int sj = ct * 16 + lr;
                int jh = sj >> 3, jw = sj & 7;
                #pragma unroll
                for (int j = 0; j < 4; ++j) {
                    int si = wave * 16 + lk * 4 + j;
                    int ih = si >> 3, iw = si & 7;
                    float v = sv[ct][j] + rpbs[((ih - jh + 7) * 15 + (iw - jw + 7)) * 6 + h];
                    if (edge) {
                        int hri = (wh << 3) + ih, wri = (ww << 3) + iw;
                        int hrj = (wh << 3) + jh, wrj = (ww << 3) + jw;
                        int ri = (hri < 120 ? 0 : (hri < 124 ? 1 : 2)) * 3 + (wri < 120 ? 0 : (wri < 124 ? 1 : 2));
                        int rj = (hrj < 120 ? 0 : (hrj < 124 ? 1 : 2)) * 3 + (wrj < 120 ? 0 : (wrj < 124 ? 1 : 2));
                        if (ri != rj) v -= 100.f;
                    }
                    sv[ct][j] = v;
                }
            }
        }
        __syncthreads();
        #pragma unroll
        for (int j = 0; j < 4; ++j) {
            float mx = fmaxf(fmaxf(sv[0][j], sv[1][j]), fmaxf(sv[2][j], sv[3][j]));
            mx = fmaxf(mx, __shfl_xor(mx, 1));
            mx = fmaxf(mx, __shfl_xor(mx, 2));
            mx = fmaxf(mx, __shfl_xor(mx, 4));
            mx = fmaxf(mx, __shfl_xor(mx, 8));
            float e0 = __expf(sv[0][j] - mx);
            float e1 = __expf(sv[1][j] - mx);
            float e2 = __expf(sv[2][j] - mx);
            float e3 = __expf(sv[3][j] - mx);
            float sm = e0 + e1 + e2 + e3;
            sm += __shfl_xor(sm, 1);
            sm += __shfl_xor(sm, 2);
            sm += __shfl_xor(sm, 4);
            sm += __shfl_xor(sm, 8);
            float inv = 1.f / sm;
            int row = wave * 16 + lk * 4 + j;
            Pb[row * 72 +      lr] = f2b(e0 * inv);
            Pb[row * 72 + 16 + lr] = f2b(e1 * inv);
            Pb[row * 72 + 32 + lr] = f2b(e2 * inv);
            Pb[row * 72 + 48 + lr] = f2b(e3 * inv);
        }
        __syncthreads();
        {
            s16x8 pa0 = *(const s16x8*)&Pb[(wave * 16 + lr) * 72 + lk * 8];
            s16x8 pa1 = *(const s16x8*)&Pb[(wave * 16 + lr) * 72 + 32 + lk * 8];
            #pragma unroll
            for (int ct = 0; ct < 2; ++ct) {
                f32x4 acc = {0.f, 0.f, 0.f, 0.f};
                s16x8 vb0 = *(const s16x8*)&Vt[(ct * 16 + lr) * 72 + lk * 8];
                s16x8 vb1 = *(const s16x8*)&Vt[(ct * 16 + lr) * 72 + 32 + lk * 8];
                acc = __builtin_amdgcn_mfma_f32_16x16x32_bf16(pa0, vb0, acc, 0, 0, 0);
                acc = __builtin_amdgcn_mfma_f32_16x16x32_bf16(pa1, vb1, acc, 0, 0, 0);
                int dd = ct * 16 + lr;
                if (dd < DH) {
                    #pragma unroll
                    for (int j = 0; j < 4; ++j) {
                        int tok = wave * 16 + lk * 4 + j;
                        outp[wbase + (size_t)tok * CD + h * DH + dd] = f2b(acc[j]);
                    }
                }
            }
        }
        __syncthreads();
    }
}

// ---------------- proj + addback + fused LN2, zero-LDS, float4 NCHW I/O
__global__ __launch_bounds__(256) void proj_ln2(
    const u16* __restrict__ oute, const u16* __restrict__ outb,
    const u16* __restrict__ sig_base, const u16* __restrict__ wp_base,
    const float* __restrict__ bias_e, const float* __restrict__ bias_b,
    const float* __restrict__ e_f, const float* __restrict__ b_f,
    const float* __restrict__ g2e, const float* __restrict__ be2e,
    const float* __restrict__ g2b, const float* __restrict__ be2b,
    float* __restrict__ xout_base, u16* __restrict__ xln_base) {
    int bid = blockIdx.x, t = threadIdx.x;
    int flag = bid >> 10;
    int rb = bid & 1023;
    const u16* sig = sig_base + (size_t)flag * S192;
    const u16* Wb = wp_base + flag * (192 * 384);
    const float* bias = flag ? bias_b : bias_e;
    const float* src = flag ? b_f : e_f;
    const float* gamma = flag ? g2b : g2e;
    const float* beta2 = flag ? be2b : be2e;
    float* xout = xout_base + (size_t)flag * XSZ;
    u16* xln = xln_base + (size_t)flag * S192;
    size_t rb64 = (size_t)rb * 64;
    int wave = t >> 6, lane = t & 63, lr = lane & 15, lk = lane >> 4;
    int row = wave * 16 + lr;

    // ---- direct gated A-fragments (K=384 split layout, seam-free)
    const u16* oe_row = oute + (rb64 + row) * (size_t)CD;
    const u16* ob_row = outb + (rb64 + row) * (size_t)CD;
    const u16* sg_row = sig + (rb64 + row) * (size_t)CP;
    s16x8 a[12];
    #pragma unroll
    for (int ks = 0; ks < 12; ++ks) {
        int koff = (ks >= 6 ? ks - 6 : ks) * 32 + lk * 8;   // 0..184
        const u16* sp = (ks < 6) ? oe_row : ob_row;
        s16x8 v = *(const s16x8*)&sp[koff];
        s16x8 g = *(const s16x8*)&sg_row[koff];
        s16x8 r;
        #pragma unroll
        for (int e = 0; e < 8; ++e) {
            float p = b2f((u16)v[e]) * b2f((u16)g[e]);
            if ((ks == 5 || ks == 11) && (koff + e >= 180)) p = 0.f;
            r[e] = (short)f2b(p);
        }
        a[ks] = r;
    }

    // ---- spatial address (same hh for j=0..3; w contiguous, wrap-safe)
    int rowm0 = (int)rb64 + wave * 16 + lk * 4;
    int win = rowm0 >> 6, pos0 = rowm0 & 63;
    int bb_ = win >> 8, whh = (win >> 4) & 15, www = win & 15;
    int hh = (((whh << 3) + (pos0 >> 3)) + 4) & 127;
    int w20 = (((www << 3) + (pos0 & 7)) + 4) & 127;
    size_t sbase = (((size_t)bb_ * CD) << 14) + (hh << 7) + w20;

    f32x4 val[12];
    float s0 = 0.f, s1 = 0.f, s2 = 0.f, s3 = 0.f;
    float q0 = 0.f, q1 = 0.f, q2 = 0.f, q3 = 0.f;
    #pragma unroll
    for (int ct = 0; ct < 12; ++ct) {
        f32x4 acc = {0.f, 0.f, 0.f, 0.f};
        #pragma unroll
        for (int ks = 0; ks < 12; ++ks) {
            s16x8 b = *(const s16x8*)&Wb[((size_t)(ct * 12 + ks) * 64 + lane) * 8];
            acc = __builtin_amdgcn_mfma_f32_16x16x32_bf16(a[ks], b, acc, 0, 0, 0);
        }
        int c = ct * 16 + lr;
        if (c < CD) {
            float bv = bias[c];
            size_t idx0 = sbase + ((size_t)c << 14);
            float4 s4 = *(const float4*)&src[idx0];
            f32x4 x;
            x[0] = s4.x + acc[0] + bv;
            x[1] = s4.y + acc[1] + bv;
            x[2] = s4.z + acc[2] + bv;
            x[3] = s4.w + acc[3] + bv;
            *(float4*)&xout[idx0] = make_float4(x[0], x[1], x[2], x[3]);
            val[ct] = x;
            s0 += x[0]; q0 += x[0] * x[0];
            s1 += x[1]; q1 += x[1] * x[1];
            s2 += x[2]; q2 += x[2] * x[2];
            s3 += x[3]; q3 += x[3] * x[3];
        } else {
            val[ct] = (f32x4){0.f, 0.f, 0.f, 0.f};
        }
    }
    // reduce row sums over the 16-lane lr group
    #pragma unroll
    for (int m = 1; m < 16; m <<= 1) {
        s0 += __shfl_xor(s0, m); q0 += __shfl_xor(q0, m);
        s1 += __shfl_xor(s1, m); q1 += __shfl_xor(q1, m);
        s2 += __shfl_xor(s2, m); q2 += __shfl_xor(q2, m);
        s3 += __shfl_xor(s3, m); q3 += __shfl_xor(q3, m);
    }
    float mean[4], rstd[4];
    mean[0] = s0 * (1.f / CD); rstd[0] = rsqrtf(q0 * (1.f / CD) - mean[0] * mean[0] + 1e-5f);
    mean[1] = s1 * (1.f / CD); rstd[1] = rsqrtf(q1 * (1.f / CD) - mean[1] * mean[1] + 1e-5f);
    mean[2] = s2 * (1.f / CD); rstd[2] = rsqrtf(q2 * (1.f / CD) - mean[2] * mean[2] + 1e-5f);
    mean[3] = s3 * (1.f / CD); rstd[3] = rsqrtf(q3 * (1.f / CD) - mean[3] * mean[3] + 1e-5f);
    // write normalized xln (bf16, WINDOWED row order, stride CP; pad cols = 0)
    #pragma unroll
    for (int ct = 0; ct < 12; ++ct) {
        int c = ct * 16 + lr;
        float g = 0.f, be = 0.f;
        if (c < CD) { g = gamma[c]; be = beta2[c]; }
        #pragma unroll
        for (int j = 0; j < 4; ++j) {
            size_t rowm = rb64 + wave * 16 + lk * 4 + j;
            u16 o = 0;
            if (c < CD) o = f2b((val[ct][j] - mean[j]) * rstd[j] * g + be);
            xln[rowm * CP + c] = o;
        }
    }
}

// ---------------- MFMA MLP v8: 32-row blocks, fragment-major Xs+Hid (20480 B)
// Same proven v6 structure (6 chunks x 128 cols, 2-ctg GEMM1, 12 barriers),
// m-extent halved -> 8 blocks/CU.
__global__ __launch_bounds__(256, 8) void mlp3(
    const u16* __restrict__ xln_base, const u16* __restrict__ w1_base,
    const float* __restrict__ b1_e, const float* __restrict__ b1_b,
    const u16* __restrict__ w2_base, const float* __restrict__ b2_e,
    const float* __restrict__ b2_b, float* __restrict__ xout_base) {
    __shared__ __align__(16) u16 Xs[6 * 2 * 64 * 8];    // 12288 B
    __shared__ __align__(16) u16 Hid[4 * 2 * 64 * 8];   //  8192 B  (total 20480)
    int bid = blockIdx.x, t = threadIdx.x;
    int flag = bid >> 11;
    int rb = bid & 2047;
    const u16* xln = xln_base + (size_t)flag * S192;
    const u16* W1p = w1_base + (size_t)flag * (768 * 192);
    const u16* W2p = w2_base + (size_t)flag * (192 * 768);
    const float* b1 = flag ? b1_b : b1_e;
    const float* b2v = flag ? b2_b : b2_e;
    float* xout = xout_base + (size_t)flag * XSZ;
    int wave = t >> 6, lane = t & 63, lr = lane & 15, lk = lane >> 4;

    // stage 32 rows of X in fragment-major order (coalesced global reads)
    for (int i = t; i < 32 * 24; i += 256) {
        int row = i / 24, seg = i % 24;                  // col = seg*8
        int sks = seg >> 2, slk = seg & 3;
        int sm = row >> 4, slr = row & 15;
        *(s16x8*)&Xs[(((sks * 2 + sm) * 64) + (slk * 16 + slr)) * 8] =
            *(const s16x8*)&xln[((size_t)rb * 32 + row) * CP + seg * 8];
    }
    __syncthreads();

    f32x4 acc2[3][2];
    #pragma unroll
    for (int c = 0; c < 3; ++c)
        #pragma unroll
        for (int m = 0; m < 2; ++m) acc2[c][m] = (f32x4){0.f, 0.f, 0.f, 0.f};

    for (int ch = 0; ch < 6; ++ch) {
        // ---- GEMM1: this wave computes hid cols [ch*128 + wave*32, +32) for ALL 32 rows
        int ctg0 = ch * 8 + wave * 2, ctg1 = ctg0 + 1;
        f32x4 h0[2], h1[2];
        #pragma unroll
        for (int m = 0; m < 2; ++m) { h0[m] = (f32x4){0,0,0,0}; h1[m] = (f32x4){0,0,0,0}; }
        #pragma unroll
        for (int ks = 0; ks < 6; ++ks) {
            s16x8 b0 = *(const s16x8*)&W1p[((size_t)(ctg0 * 6 + ks) * 64 + lane) * 8];
            s16x8 b1v = *(const s16x8*)&W1p[((size_t)(ctg1 * 6 + ks) * 64 + lane) * 8];
            #pragma unroll
            for (int m = 0; m < 2; ++m) {
                s16x8 av = *(const s16x8*)&Xs[((ks * 2 + m) * 64 + lane) * 8];  // conflict-free
                h0[m] = __builtin_amdgcn_mfma_f32_16x16x32_bf16(av, b0, h0[m], 0, 0, 0);
                h1[m] = __builtin_amdgcn_mfma_f32_16x16x32_bf16(av, b1v, h1[m], 0, 0, 0);
            }
        }
        #pragma unroll 2
        for (int cti = 0; cti < 2; ++cti) {
            int hcol = (ctg0 + cti) * 16 + lr;
            float bb = (hcol < 720) ? b1[hcol] : 0.f;
            int lcol = wave * 32 + cti * 16 + lr;        // chunk-local col 0..127
            int ksr = lcol >> 5, lkr = (lcol >> 3) & 3, er = lcol & 7;
            #pragma unroll
            for (int m = 0; m < 2; ++m) {
                f32x4 hv = cti ? h1[m] : h0[m];
                #pragma unroll
                for (int j = 0; j < 4; ++j) {
                    float v = gelu_f(hv[j] + bb);
                    Hid[(((ksr * 2 + m) * 64) + (lkr * 16 + lk * 4 + j)) * 8 + er] = f2b(v);
                }
            }
        }
        __syncthreads();
        // ---- GEMM2: this wave computes out cols [wave*48, +48) over this chunk's 128 K
        #pragma unroll
        for (int ks = 0; ks < 4; ++ks) {
            int gks = ch * 4 + ks;
            s16x8 av[2];
            #pragma unroll
            for (int m = 0; m < 2; ++m)
                av[m] = *(const s16x8*)&Hid[((ks * 2 + m) * 64 + lane) * 8];    // conflict-free
            #pragma unroll
            for (int ct3 = 0; ct3 < 3; ++ct3) {
                int ctg = wave * 3 + ct3;
                s16x8 b = *(const s16x8*)&W2p[((size_t)(ctg * 24 + gks) * 64 + lane) * 8];
                #pragma unroll
                for (int m = 0; m < 2; ++m)
                    acc2[ct3][m] = __builtin_amdgcn_mfma_f32_16x16x32_bf16(av[m], b, acc2[ct3][m], 0, 0, 0);
            }
        }
        __syncthreads();
    }
    // ---- epilogue: float4 RMW into xout (NCHW); windowed row -> spatial
    #pragma unroll
    for (int m = 0; m < 2; ++m) {
        int mm0 = rb * 32 + m * 16 + lk * 4;        // windowed row of j=0
        int win = mm0 >> 6, pos0 = mm0 & 63;
        int b = win >> 8, whh = (win >> 4) & 15, www = win & 15;
        int hh = (((whh << 3) + (pos0 >> 3)) + 4) & 127;
        int w20 = (((www << 3) + (pos0 & 7)) + 4) & 127;
        size_t sbase = (((size_t)b * CD) << 14) + (hh << 7) + w20;
        #pragma unroll
        for (int ct3 = 0; ct3 < 3; ++ct3) {
            int cc = (wave * 3 + ct3) * 16 + lr;
            if (cc < CD) {
                float bb = b2v[cc];
                size_t idx0 = sbase + ((size_t)cc << 14);
                float4 o4 = *(const float4*)&xout[idx0];
                o4.x += acc2[ct3][m][0] + bb;
                o4.y += acc2[ct3][m][1] + bb;
                o4.z += acc2[ct3][m][2] + bb;
                o4.w += acc2[ct3][m][3] + bb;
                *(float4*)&xout[idx0] = o4;
            }
        }
    }
}

extern "C" void kernel_launch(void* const* d_in, const int* in_sizes, int n_in,
                              void* d_out, int out_size, void* d_ws, size_t ws_size,
                              hipStream_t stream) {
    const float* e_f = (const float*)d_in[0];
    const float* b_f = (const float*)d_in[1];

    u16* ew   = (u16*)d_ws;
    u16* bw   = ew + S192;
    u16* sige = bw + S192;
    u16* sigb = sige + S192;
    u16* oute = sigb + S192;
    u16* outb = oute + S180;
    u16* wg_e = outb + S180;                 // contiguous prep region
    u16* wp_e = wg_e + 2 * 36864;
    u16* w1_e = wp_e + 2 * 73728;
    u16* w2_e = w1_e + 2 * 147456;
    u16* wq_e = w2_e + 2 * 147456;           // 2 * 576*192
    float* bq_e = (float*)(wq_e + 2 * 576 * 192);   // 2 * 576
    u16* lne = sige;   // xln (from proj_ln2) overwrites sig region

    float* xe = (float*)d_out;

    PrepArgs pa;
    pa.s0 = (const float*)d_in[10];
    pa.s1 = (const float*)d_in[12];
    pa.s2 = (const float*)d_in[15];
    pa.s3 = (const float*)d_in[17];
    pa.s4 = (const float*)d_in[23];
    pa.s5 = (const float*)d_in[27];
    pa.s6 = (const float*)d_in[25];
    pa.s7 = (const float*)d_in[29];
    pa.dst = wg_e;
    prep_all<<<3168, 256, 0, stream>>>(pa);
    prep_wqkv2<<<(2 * 576 * 192 + 255) / 256, 256, 0, stream>>>(
        (const float*)d_in[6], (const float*)d_in[7],
        (const float*)d_in[8], (const float*)d_in[9], wq_e, bq_e);

    ln_win2<<<2 * NWIN, 256, 0, stream>>>(e_f, b_f,
        (const float*)d_in[2], (const float*)d_in[3],
        (const float*)d_in[4], (const float*)d_in[5], ew);

    gate2<<<2 * MROWS / 64, 256, 0, stream>>>(ew, wg_e,
        (const float*)d_in[11], (const float*)d_in[13], sige);

    attn2<<<2 * NWIN, 256, 0, stream>>>(ew, wq_e, bq_e,
        (const float*)d_in[14], oute);

    proj_ln2<<<2 * MROWS / 64, 256, 0, stream>>>(oute, outb, sige, wp_e,
        (const float*)d_in[16], (const float*)d_in[18], e_f, b_f,
        (const float*)d_in[19], (const float*)d_in[20],
        (const float*)d_in[21], (const float*)d_in[22], xe, lne);

    mlp3<<<2 * MROWS / 32, 256, 0, stream>>>(lne, w1_e,
        (const float*)d_in[24], (const float*)d_in[28], w2_e,
        (const float*)d_in[26], (const float*)d_in[30], xe);
}

// Round 14
// 712.207 us; speedup vs baseline: 1.1322x; 1.1322x over previous
//
#include <hip/hip_runtime.h>
#include <hip/hip_bf16.h>

typedef unsigned short u16;
typedef unsigned int u32;
typedef __attribute__((ext_vector_type(8))) short s16x8;
typedef __attribute__((ext_vector_type(4))) float f32x4;

constexpr int CD    = 180;
constexpr int CP    = 192;              // K-padded channel count
constexpr int BATCH = 4;
constexpr int RES   = 128;
constexpr int LSZ   = RES * RES;        // 16384
constexpr int NHEAD = 6;
constexpr int DH    = 30;
constexpr int NTOK  = 64;
constexpr int NWIN  = 1024;
constexpr int MROWS = NWIN * NTOK;      // 65536
constexpr size_t S192 = (size_t)MROWS * CP;
constexpr size_t S180 = (size_t)MROWS * CD;
constexpr size_t XSZ  = (size_t)BATCH * CD * LSZ;

__device__ __forceinline__ float b2f(u16 u) { return __uint_as_float(((u32)u) << 16); }
__device__ __forceinline__ u16 f2b(float f) {
    __hip_bfloat16 h = __float2bfloat16(f);
    return *reinterpret_cast<u16*>(&h);
}
// fast GELU (tanh form); |err vs exact erf-GELU| <~1e-3
__device__ __forceinline__ float gelu_f(float x) {
    float y = 0.7978845608028654f * (x + 0.044715f * x * x * x);
    float t = __expf(-2.f * fabsf(y));
    float th = (1.f - t) / (1.f + t);
    th = copysignf(th, y);
    return 0.5f * x * (1.f + th);
}

// ---------------- merged weight prep: 8 fragment-major jobs in one launch
struct PrepArgs {
    const float *s0, *s1, *s2, *s3, *s4, *s5, *s6, *s7;
    u16* dst;   // base of contiguous dst region (wg_e)
};
__device__ __forceinline__ void do_frag(const float* __restrict__ src,
        u16* __restrict__ dst, int N, int K, int nks, int li) {
    int e = li & 7, lr = (li >> 3) & 15, lk = (li >> 7) & 3, rest = li >> 9;
    int ks = rest % nks, ct = rest / nks;
    int n = ct * 16 + lr, k = ks * 32 + lk * 8 + e;
    float v = (n < N && k < K) ? src[n * K + k] : 0.f;
    dst[li] = f2b(v);
}
// proj weights: K=384 split layout (oute cols 0-191 pad, outb 192-383 pad)
__device__ __forceinline__ void do_frag_proj(const float* __restrict__ src,
        u16* __restrict__ dst, int li) {
    int e = li & 7, lr = (li >> 3) & 15, lk = (li >> 7) & 3, rest = li >> 9;
    int ks = rest % 12, ct = rest / 12;
    int n = ct * 16 + lr, k = ks * 32 + lk * 8 + e;
    int khalf = k & 191;
    int ksrc = (k < 192) ? khalf : 180 + khalf;
    float v = (n < 180 && khalf < 180) ? src[n * 360 + ksrc] : 0.f;
    dst[li] = f2b(v);
}
__global__ __launch_bounds__(256) void prep_all(PrepArgs pa) {
    int bid = blockIdx.x, t = threadIdx.x;
    if (bid < 144)       do_frag(pa.s0, pa.dst,          180, 180,  6, (bid       ) * 256 + t);
    else if (bid < 288)  do_frag(pa.s1, pa.dst + 36864,  180, 180,  6, (bid - 144 ) * 256 + t);
    else if (bid < 576)  do_frag_proj(pa.s2, pa.dst + 73728,           (bid - 288 ) * 256 + t);
    else if (bid < 864)  do_frag_proj(pa.s3, pa.dst + 147456,          (bid - 576 ) * 256 + t);
    else if (bid < 1440) do_frag(pa.s4, pa.dst + 221184, 720, 180,  6, (bid - 864 ) * 256 + t);
    else if (bid < 2016) do_frag(pa.s5, pa.dst + 368640, 720, 180,  6, (bid - 1440) * 256 + t);
    else if (bid < 2592) do_frag(pa.s6, pa.dst + 516096, 180, 720, 24, (bid - 2016) * 256 + t);
    else                 do_frag(pa.s7, pa.dst + 663552, 180, 720, 24, (bid - 2592) * 256 + t);
}

// ---------------- merged qkv weight prep (e and b)
__global__ __launch_bounds__(256) void prep_wqkv2(
        const float* __restrict__ we, const float* __restrict__ be,
        const float* __restrict__ wb, const float* __restrict__ bb,
        u16* __restrict__ wp_base, float* __restrict__ bp_base) {
    int gi = blockIdx.x * 256 + threadIdx.x;
    int flag = gi >= 576 * 192;
    int i = flag ? gi - 576 * 192 : gi;
    if (i >= 576 * 192) return;
    const float* w = flag ? wb : we;
    const float* bsrc = flag ? bb : be;
    u16* wp = wp_base + (size_t)flag * (576 * 192);
    float* bp = bp_base + flag * 576;
    int e = i & 7, lr = (i >> 3) & 15, lk = (i >> 7) & 3, rest = i >> 9;
    int ks = rest % 6, rest2 = rest / 6;
    int ct = rest2 % 6, head = rest2 / 6;
    int rr = ct * 16 + lr;
    int sec = rr >> 5, dd = rr & 31;
    int srow = sec * 180 + head * 30 + dd;
    int k = ks * 32 + lk * 8 + e;
    float scale = (sec == 0) ? 0.18257418583505536f : 1.f;
    float v = (dd < 30 && k < 180) ? w[srow * 180 + k] * scale : 0.f;
    wp[i] = f2b(v);
    if (ks == 0 && lk == 0 && e == 0)
        bp[head * 96 + rr] = (dd < 30) ? bsrc[srow] * scale : 0.f;
}

// ---------------- merged LN1 + roll + window partition (e and b)
__global__ __launch_bounds__(256) void ln_win2(
    const float* __restrict__ e_f, const float* __restrict__ b_f,
    const float* __restrict__ g_e, const float* __restrict__ be_e,
    const float* __restrict__ g_b, const float* __restrict__ be_b,
    u16* __restrict__ dst_base) {
    __shared__ float tile[NTOK][CD + 1];
    int bid = blockIdx.x;
    int flag = bid >> 10;
    int widx = bid & 1023;
    const float* src = flag ? b_f : e_f;
    const float* gamma = flag ? g_b : g_e;
    const float* beta = flag ? be_b : be_e;
    u16* dst = dst_base + (size_t)flag * S192;
    int b = widx >> 8, wrem = widx & 255;
    int wh = wrem >> 4, ww = wrem & 15;
    int t = threadIdx.x;
    for (int i = t; i < NTOK * CD; i += 256) {
        int c = i >> 6, pos = i & 63;
        int sh = ((wh << 3) + (pos >> 3) + 4) & 127;
        int sw = ((ww << 3) + (pos & 7) + 4) & 127;
        tile[pos][c] = src[(((size_t)b * CD + c) << 14) + (sh << 7) + sw];
    }
    __syncthreads();
    int pos = t >> 2, sub = t & 3;
    float s = 0.f, ss = 0.f;
    for (int k = 0; k < 45; ++k) {
        float v = tile[pos][sub * 45 + k];
        s += v; ss += v * v;
    }
    s += __shfl_xor(s, 1); ss += __shfl_xor(ss, 1);
    s += __shfl_xor(s, 2); ss += __shfl_xor(ss, 2);
    float mean = s * (1.f / CD);
    float rstd = rsqrtf(ss * (1.f / CD) - mean * mean + 1e-5f);
    size_t obase = ((size_t)widx * NTOK + pos) * CP;
    for (int k = 0; k < 45; ++k) {
        int c = sub * 45 + k;
        dst[obase + c] = f2b((tile[pos][c] - mean) * rstd * gamma[c] + beta[c]);
    }
    if (sub == 3) {
        for (int k = 0; k < 12; ++k) dst[obase + CD + k] = 0;
    }
}

// ---------------- merged MFMA attention (e and b) + fused sigmoid gate
__global__ __launch_bounds__(256) void attn2(
    const u16* __restrict__ ew_base, const u16* __restrict__ wq_base,
    const float* __restrict__ bq_base, const float* __restrict__ rpb,
    const u16* __restrict__ wg_base, const float* __restrict__ gbias_e,
    const float* __restrict__ gbias_b, u16* __restrict__ sig_base,
    u16* __restrict__ out_base) {
    __shared__ __align__(16) char smem[28448];
    u16*   ews  = (u16*)smem;                 // 64*200*2 = 25600 B (staging, dies)
    u16*   Qs   = (u16*)smem;                 // 64*36*2  =  4608
    u16*   Ks   = (u16*)(smem + 4608);
    u16*   Vt   = (u16*)(smem + 9216);        // 32*72*2  =  4608
    u16*   Pb   = (u16*)(smem + 13824);       // 64*72*2  =  9216
    float* rpbs = (float*)(smem + 23040);     // 1350*4   =  5400

    int bid = blockIdx.x;
    int flag = bid >> 10;
    int widx = bid & 1023;
    const u16* ew = ew_base + (size_t)flag * S192;
    const u16* Wq = wq_base + (size_t)flag * (576 * 192);
    const float* Bq = bq_base + flag * 576;
    u16* outp = out_base + (size_t)flag * S180;

    int wrem = widx & 255;
    int wh = wrem >> 4, ww = wrem & 15;
    bool edge = (wh == 15) || (ww == 15);
    int t = threadIdx.x;
    size_t wbase = (size_t)widx * NTOK * CD;
    size_t wb192 = (size_t)widx * NTOK * CP;

    for (int i = t; i < 64 * 24; i += 256) {
        int row = i / 24, seg = i % 24;
        *(s16x8*)&ews[row * 200 + seg * 8] = *(const s16x8*)&ew[wb192 + (size_t)row * CP + seg * 8];
    }
    __syncthreads();

    int wave = t >> 6, lane = t & 63, lr = lane & 15, lk = lane >> 4;
    s16x8 a[6];
    #pragma unroll
    for (int ks = 0; ks < 6; ++ks)
        a[ks] = *(const s16x8*)&ews[(wave * 16 + lr) * 200 + ks * 32 + lk * 8];
    __syncthreads();   // all waves done reading ews; region reusable

    for (int i = t; i < 1350; i += 256) rpbs[i] = rpb[i];  // visible after next barrier

    // ---- fused gate: sig = sigmoid(ew @ Wg^T + gbias), register/global only
    {
        const u16* Wg = wg_base + flag * 36864;
        const float* gbias = flag ? gbias_b : gbias_e;
        u16* sig = sig_base + (size_t)flag * S192;
        for (int ct = 0; ct < 12; ++ct) {
            f32x4 acc = {0.f, 0.f, 0.f, 0.f};
            #pragma unroll
            for (int ks = 0; ks < 6; ++ks) {
                s16x8 b = *(const s16x8*)&Wg[((size_t)(ct * 6 + ks) * 64 + lane) * 8];
                acc = __builtin_amdgcn_mfma_f32_16x16x32_bf16(a[ks], b, acc, 0, 0, 0);
            }
            int c = ct * 16 + lr;
            if (c < CD) {
                float bb = gbias[c];
                #pragma unroll
                for (int j = 0; j < 4; ++j) {
                    int rowm = widx * 64 + wave * 16 + lk * 4 + j;
                    float v = acc[j] + bb;
                    v = 1.f / (1.f + __expf(-v));
                    sig[(size_t)rowm * CP + c] = f2b(v);
                }
            }
        }
    }

    for (int h = 0; h < NHEAD; ++h) {
        #pragma unroll
        for (int ct = 0; ct < 6; ++ct) {
            f32x4 acc = {0.f, 0.f, 0.f, 0.f};
            #pragma unroll
            for (int ks = 0; ks < 6; ++ks) {
                s16x8 b = *(const s16x8*)&Wq[(((size_t)(h * 6 + ct) * 6 + ks) * 64 + lane) * 8];
                acc = __builtin_amdgcn_mfma_f32_16x16x32_bf16(a[ks], b, acc, 0, 0, 0);
            }
            int sec = ct >> 1;
            int dd = ((ct & 1) << 4) + lr;
            float bb = Bq[h * 96 + ct * 16 + lr];
            #pragma unroll
            for (int j = 0; j < 4; ++j) {
                int tok = wave * 16 + lk * 4 + j;
                float v = acc[j] + bb;
                if (sec == 0)      Qs[tok * 36 + dd] = f2b(v);
                else if (sec == 1) Ks[tok * 36 + dd] = f2b(v);
                else               Vt[dd * 72 + tok] = f2b(v);
            }
        }
        __syncthreads();
        f32x4 sv[4];
        {
            s16x8 qa = *(const s16x8*)&Qs[(wave * 16 + lr) * 36 + lk * 8];
            #pragma unroll
            for (int ct = 0; ct < 4; ++ct) {
                s16x8 kb = *(const s16x8*)&Ks[(ct * 16 + lr) * 36 + lk * 8];
                f32x4 z = {0.f, 0.f, 0.f, 0.f};
                sv[ct] = __builtin_amdgcn_mfma_f32_16x16x32_bf16(qa, kb, z, 0, 0, 0);
            }
            #pragma unroll
            for (int ct = 0; ct < 4; ++ct) {
                int sj = ct * 16 + lr;
                int jh = sj >> 3, jw = sj & 7;
                #pragma unroll
                for (int j = 0; j < 4; ++j) {
                    int si = wave * 16 + lk * 4 + j;
                    int ih = si >> 3, iw = si & 7;
                    float v = sv[ct][j] + rpbs[((ih - jh + 7) * 15 + (iw - jw + 7)) * 6 + h];
                    if (edge) {
                        int hri = (wh << 3) + ih, wri = (ww << 3) + iw;
                        int hrj = (wh << 3) + jh, wrj = (ww << 3) + jw;
                        int ri = (hri < 120 ? 0 : (hri < 124 ? 1 : 2)) * 3 + (wri < 120 ? 0 : (wri < 124 ? 1 : 2));
                        int rj = (hrj < 120 ? 0 : (hrj < 124 ? 1 : 2)) * 3 + (wrj < 120 ? 0 : (wrj < 124 ? 1 : 2));
                        if (ri != rj) v -= 100.f;
                    }
                    sv[ct][j] = v;
                }
            }
        }
        __syncthreads();
        #pragma unroll
        for (int j = 0; j < 4; ++j) {
            float mx = fmaxf(fmaxf(sv[0][j], sv[1][j]), fmaxf(sv[2][j], sv[3][j]));
            mx = fmaxf(mx, __shfl_xor(mx, 1));
            mx = fmaxf(mx, __shfl_xor(mx, 2));
            mx = fmaxf(mx, __shfl_xor(mx, 4));
            mx = fmaxf(mx, __shfl_xor(mx, 8));
            float e0 = __expf(sv[0][j] - mx);
            float e1 = __expf(sv[1][j] - mx);
            float e2 = __expf(sv[2][j] - mx);
            float e3 = __expf(sv[3][j] - mx);
            float sm = e0 + e1 + e2 + e3;
            sm += __shfl_xor(sm, 1);
            sm += __shfl_xor(sm, 2);
            sm += __shfl_xor(sm, 4);
            sm += __shfl_xor(sm, 8);
            float inv = 1.f / sm;
            int row = wave * 16 + lk * 4 + j;
            Pb[row * 72 +      lr] = f2b(e0 * inv);
            Pb[row * 72 + 16 + lr] = f2b(e1 * inv);
            Pb[row * 72 + 32 + lr] = f2b(e2 * inv);
            Pb[row * 72 + 48 + lr] = f2b(e3 * inv);
        }
        __syncthreads();
        {
            s16x8 pa0 = *(const s16x8*)&Pb[(wave * 16 + lr) * 72 + lk * 8];
            s16x8 pa1 = *(const s16x8*)&Pb[(wave * 16 + lr) * 72 + 32 + lk * 8];
            #pragma unroll
            for (int ct = 0; ct < 2; ++ct) {
                f32x4 acc = {0.f, 0.f, 0.f, 0.f};
                s16x8 vb0 = *(const s16x8*)&Vt[(ct * 16 + lr) * 72 + lk * 8];
                s16x8 vb1 = *(const s16x8*)&Vt[(ct * 16 + lr) * 72 + 32 + lk * 8];
                acc = __builtin_amdgcn_mfma_f32_16x16x32_bf16(pa0, vb0, acc, 0, 0, 0);
                acc = __builtin_amdgcn_mfma_f32_16x16x32_bf16(pa1, vb1, acc, 0, 0, 0);
                int dd = ct * 16 + lr;
                if (dd < DH) {
                    #pragma unroll
                    for (int j = 0; j < 4; ++j) {
                        int tok = wave * 16 + lk * 4 + j;
                        outp[wbase + (size_t)tok * CD + h * DH + dd] = f2b(acc[j]);
                    }
                }
            }
        }
        __syncthreads();
    }
}

// ---------------- proj + addback + fused LN2, zero-LDS, float4 NCHW I/O
__global__ __launch_bounds__(256) void proj_ln2(
    const u16* __restrict__ oute, const u16* __restrict__ outb,
    const u16* __restrict__ sig_base, const u16* __restrict__ wp_base,
    const float* __restrict__ bias_e, const float* __restrict__ bias_b,
    const float* __restrict__ e_f, const float* __restrict__ b_f,
    const float* __restrict__ g2e, const float* __restrict__ be2e,
    const float* __restrict__ g2b, const float* __restrict__ be2b,
    float* __restrict__ xout_base, u16* __restrict__ xln_base) {
    int bid = blockIdx.x, t = threadIdx.x;
    int flag = bid >> 10;
    int rb = bid & 1023;
    const u16* sig = sig_base + (size_t)flag * S192;
    const u16* Wb = wp_base + flag * (192 * 384);
    const float* bias = flag ? bias_b : bias_e;
    const float* src = flag ? b_f : e_f;
    const float* gamma = flag ? g2b : g2e;
    const float* beta2 = flag ? be2b : be2e;
    float* xout = xout_base + (size_t)flag * XSZ;
    u16* xln = xln_base + (size_t)flag * S192;
    size_t rb64 = (size_t)rb * 64;
    int wave = t >> 6, lane = t & 63, lr = lane & 15, lk = lane >> 4;
    int row = wave * 16 + lr;

    // ---- direct gated A-fragments (K=384 split layout, seam-free)
    const u16* oe_row = oute + (rb64 + row) * (size_t)CD;
    const u16* ob_row = outb + (rb64 + row) * (size_t)CD;
    const u16* sg_row = sig + (rb64 + row) * (size_t)CP;
    s16x8 a[12];
    #pragma unroll
    for (int ks = 0; ks < 12; ++ks) {
        int koff = (ks >= 6 ? ks - 6 : ks) * 32 + lk * 8;   // 0..184
        const u16* sp = (ks < 6) ? oe_row : ob_row;
        s16x8 v = *(const s16x8*)&sp[koff];
        s16x8 g = *(const s16x8*)&sg_row[koff];
        s16x8 r;
        #pragma unroll
        for (int e = 0; e < 8; ++e) {
            float p = b2f((u16)v[e]) * b2f((u16)g[e]);
            if ((ks == 5 || ks == 11) && (koff + e >= 180)) p = 0.f;
            r[e] = (short)f2b(p);
        }
        a[ks] = r;
    }

    // ---- spatial address (same hh for j=0..3; w contiguous, wrap-safe)
    int rowm0 = (int)rb64 + wave * 16 + lk * 4;
    int win = rowm0 >> 6, pos0 = rowm0 & 63;
    int bb_ = win >> 8, whh = (win >> 4) & 15, www = win & 15;
    int hh = (((whh << 3) + (pos0 >> 3)) + 4) & 127;
    int w20 = (((www << 3) + (pos0 & 7)) + 4) & 127;
    size_t sbase = (((size_t)bb_ * CD) << 14) + (hh << 7) + w20;

    f32x4 val[12];
    float s0 = 0.f, s1 = 0.f, s2 = 0.f, s3 = 0.f;
    float q0 = 0.f, q1 = 0.f, q2 = 0.f, q3 = 0.f;
    #pragma unroll
    for (int ct = 0; ct < 12; ++ct) {
        f32x4 acc = {0.f, 0.f, 0.f, 0.f};
        #pragma unroll
        for (int ks = 0; ks < 12; ++ks) {
            s16x8 b = *(const s16x8*)&Wb[((size_t)(ct * 12 + ks) * 64 + lane) * 8];
            acc = __builtin_amdgcn_mfma_f32_16x16x32_bf16(a[ks], b, acc, 0, 0, 0);
        }
        int c = ct * 16 + lr;
        if (c < CD) {
            float bv = bias[c];
            size_t idx0 = sbase + ((size_t)c << 14);
            float4 s4 = *(const float4*)&src[idx0];
            f32x4 x;
            x[0] = s4.x + acc[0] + bv;
            x[1] = s4.y + acc[1] + bv;
            x[2] = s4.z + acc[2] + bv;
            x[3] = s4.w + acc[3] + bv;
            *(float4*)&xout[idx0] = make_float4(x[0], x[1], x[2], x[3]);
            val[ct] = x;
            s0 += x[0]; q0 += x[0] * x[0];
            s1 += x[1]; q1 += x[1] * x[1];
            s2 += x[2]; q2 += x[2] * x[2];
            s3 += x[3]; q3 += x[3] * x[3];
        } else {
            val[ct] = (f32x4){0.f, 0.f, 0.f, 0.f};
        }
    }
    // reduce row sums over the 16-lane lr group
    #pragma unroll
    for (int m = 1; m < 16; m <<= 1) {
        s0 += __shfl_xor(s0, m); q0 += __shfl_xor(q0, m);
        s1 += __shfl_xor(s1, m); q1 += __shfl_xor(q1, m);
        s2 += __shfl_xor(s2, m); q2 += __shfl_xor(q2, m);
        s3 += __shfl_xor(s3, m); q3 += __shfl_xor(q3, m);
    }
    float mean[4], rstd[4];
    mean[0] = s0 * (1.f / CD); rstd[0] = rsqrtf(q0 * (1.f / CD) - mean[0] * mean[0] + 1e-5f);
    mean[1] = s1 * (1.f / CD); rstd[1] = rsqrtf(q1 * (1.f / CD) - mean[1] * mean[1] + 1e-5f);
    mean[2] = s2 * (1.f / CD); rstd[2] = rsqrtf(q2 * (1.f / CD) - mean[2] * mean[2] + 1e-5f);
    mean[3] = s3 * (1.f / CD); rstd[3] = rsqrtf(q3 * (1.f / CD) - mean[3] * mean[3] + 1e-5f);
    // write normalized xln (bf16, WINDOWED row order, stride CP; pad cols = 0)
    #pragma unroll
    for (int ct = 0; ct < 12; ++ct) {
        int c = ct * 16 + lr;
        float g = 0.f, be = 0.f;
        if (c < CD) { g = gamma[c]; be = beta2[c]; }
        #pragma unroll
        for (int j = 0; j < 4; ++j) {
            size_t rowm = rb64 + wave * 16 + lk * 4 + j;
            u16 o = 0;
            if (c < CD) o = f2b((val[ct][j] - mean[j]) * rstd[j] * g + be);
            xln[rowm * CP + c] = o;
        }
    }
}

// ---------------- MFMA MLP v6 (proven r11): fragment-major Xs+Hid (40960 B)
__global__ __launch_bounds__(256, 4) void mlp3(
    const u16* __restrict__ xln_base, const u16* __restrict__ w1_base,
    const float* __restrict__ b1_e, const float* __restrict__ b1_b,
    const u16* __restrict__ w2_base, const float* __restrict__ b2_e,
    const float* __restrict__ b2_b, float* __restrict__ xout_base) {
    __shared__ __align__(16) u16 Xs[6 * 4 * 64 * 8];    // 24576 B
    __shared__ __align__(16) u16 Hid[4 * 4 * 64 * 8];   // 16384 B  (total 40960)
    int bid = blockIdx.x, t = threadIdx.x;
    int flag = bid >> 10;
    int rb = bid & 1023;
    const u16* xln = xln_base + (size_t)flag * S192;
    const u16* W1p = w1_base + (size_t)flag * (768 * 192);
    const u16* W2p = w2_base + (size_t)flag * (192 * 768);
    const float* b1 = flag ? b1_b : b1_e;
    const float* b2v = flag ? b2_b : b2_e;
    float* xout = xout_base + (size_t)flag * XSZ;
    int wave = t >> 6, lane = t & 63, lr = lane & 15, lk = lane >> 4;

    // stage X in fragment-major order (coalesced global reads)
    for (int i = t; i < 64 * 24; i += 256) {
        int row = i / 24, seg = i % 24;                  // col = seg*8
        int sks = seg >> 2, slk = seg & 3;
        int sm = row >> 4, slr = row & 15;
        *(s16x8*)&Xs[(((sks * 4 + sm) * 64) + (slk * 16 + slr)) * 8] =
            *(const s16x8*)&xln[((size_t)rb * 64 + row) * CP + seg * 8];
    }
    __syncthreads();

    f32x4 acc2[3][4];
    #pragma unroll
    for (int c = 0; c < 3; ++c)
        #pragma unroll
        for (int m = 0; m < 4; ++m) acc2[c][m] = (f32x4){0.f, 0.f, 0.f, 0.f};

    for (int ch = 0; ch < 6; ++ch) {
        // ---- GEMM1: this wave computes hid cols [ch*128 + wave*32, +32) for ALL 64 rows
        int ctg0 = ch * 8 + wave * 2, ctg1 = ctg0 + 1;
        f32x4 h0[4], h1[4];
        #pragma unroll
        for (int m = 0; m < 4; ++m) { h0[m] = (f32x4){0,0,0,0}; h1[m] = (f32x4){0,0,0,0}; }
        #pragma unroll
        for (int ks = 0; ks < 6; ++ks) {
            s16x8 b0 = *(const s16x8*)&W1p[((size_t)(ctg0 * 6 + ks) * 64 + lane) * 8];
            s16x8 b1v = *(const s16x8*)&W1p[((size_t)(ctg1 * 6 + ks) * 64 + lane) * 8];
            #pragma unroll
            for (int m = 0; m < 4; ++m) {
                s16x8 av = *(const s16x8*)&Xs[((ks * 4 + m) * 64 + lane) * 8];  // conflict-free
                h0[m] = __builtin_amdgcn_mfma_f32_16x16x32_bf16(av, b0, h0[m], 0, 0, 0);
                h1[m] = __builtin_amdgcn_mfma_f32_16x16x32_bf16(av, b1v, h1[m], 0, 0, 0);
            }
        }
        #pragma unroll 2
        for (int cti = 0; cti < 2; ++cti) {
            int hcol = (ctg0 + cti) * 16 + lr;
            float bb = (hcol < 720) ? b1[hcol] : 0.f;
            int lcol = wave * 32 + cti * 16 + lr;        // chunk-local col 0..127
            int ksr = lcol >> 5, lkr = (lcol >> 3) & 3, er = lcol & 7;
            #pragma unroll
            for (int m = 0; m < 4; ++m) {
                f32x4 hv = cti ? h1[m] : h0[m];
                #pragma unroll
                for (int j = 0; j < 4; ++j) {
                    float v = gelu_f(hv[j] + bb);
                    Hid[(((ksr * 4 + m) * 64) + (lkr * 16 + lk * 4 + j)) * 8 + er] = f2b(v);
                }
            }
        }
        __syncthreads();
        // ---- GEMM2: this wave computes out cols [wave*48, +48) over this chunk's 128 K
        #pragma unroll
        for (int ks = 0; ks < 4; ++ks) {
            int gks = ch * 4 + ks;
            s16x8 av[4];
            #pragma unroll
            for (int m = 0; m < 4; ++m)
                av[m] = *(const s16x8*)&Hid[((ks * 4 + m) * 64 + lane) * 8];    // conflict-free
            #pragma unroll
            for (int ct3 = 0; ct3 < 3; ++ct3) {
                int ctg = wave * 3 + ct3;
                s16x8 b = *(const s16x8*)&W2p[((size_t)(ctg * 24 + gks) * 64 + lane) * 8];
                #pragma unroll
                for (int m = 0; m < 4; ++m)
                    acc2[ct3][m] = __builtin_amdgcn_mfma_f32_16x16x32_bf16(av[m], b, acc2[ct3][m], 0, 0, 0);
            }
        }
        __syncthreads();
    }
    // ---- epilogue: float4 RMW into xout (NCHW); windowed row -> spatial
    #pragma unroll
    for (int m = 0; m < 4; ++m) {
        int mm0 = rb * 64 + m * 16 + lk * 4;        // windowed row of j=0
        int win = mm0 >> 6, pos0 = mm0 & 63;
        int b = win >> 8, whh = (win >> 4) & 15, www = win & 15;
        int hh = (((whh << 3) + (pos0 >> 3)) + 4) & 127;
        int w20 = (((www << 3) + (pos0 & 7)) + 4) & 127;
        size_t sbase = (((size_t)b * CD) << 14) + (hh << 7) + w20;
        #pragma unroll
        for (int ct3 = 0; ct3 < 3; ++ct3) {
            int cc = (wave * 3 + ct3) * 16 + lr;
            if (cc < CD) {
                float bb = b2v[cc];
                size_t idx0 = sbase + ((size_t)cc << 14);
                float4 o4 = *(const float4*)&xout[idx0];
                o4.x += acc2[ct3][m][0] + bb;
                o4.y += acc2[ct3][m][1] + bb;
                o4.z += acc2[ct3][m][2] + bb;
                o4.w += acc2[ct3][m][3] + bb;
                *(float4*)&xout[idx0] = o4;
            }
        }
    }
}

extern "C" void kernel_launch(void* const* d_in, const int* in_sizes, int n_in,
                              void* d_out, int out_size, void* d_ws, size_t ws_size,
                              hipStream_t stream) {
    const float* e_f = (const float*)d_in[0];
    const float* b_f = (const float*)d_in[1];

    u16* ew   = (u16*)d_ws;
    u16* bw   = ew + S192;
    u16* sige = bw + S192;
    u16* sigb = sige + S192;
    u16* oute = sigb + S192;
    u16* outb = oute + S180;
    u16* wg_e = outb + S180;                 // contiguous prep region
    u16* wp_e = wg_e + 2 * 36864;
    u16* w1_e = wp_e + 2 * 73728;
    u16* w2_e = w1_e + 2 * 147456;
    u16* wq_e = w2_e + 2 * 147456;           // 2 * 576*192
    float* bq_e = (float*)(wq_e + 2 * 576 * 192);   // 2 * 576
    u16* lne = sige;   // xln (from proj_ln2) overwrites sig region

    float* xe = (float*)d_out;

    PrepArgs pa;
    pa.s0 = (const float*)d_in[10];
    pa.s1 = (const float*)d_in[12];
    pa.s2 = (const float*)d_in[15];
    pa.s3 = (const float*)d_in[17];
    pa.s4 = (const float*)d_in[23];
    pa.s5 = (const float*)d_in[27];
    pa.s6 = (const float*)d_in[25];
    pa.s7 = (const float*)d_in[29];
    pa.dst = wg_e;
    prep_all<<<3168, 256, 0, stream>>>(pa);
    prep_wqkv2<<<(2 * 576 * 192 + 255) / 256, 256, 0, stream>>>(
        (const float*)d_in[6], (const float*)d_in[7],
        (const float*)d_in[8], (const float*)d_in[9], wq_e, bq_e);

    ln_win2<<<2 * NWIN, 256, 0, stream>>>(e_f, b_f,
        (const float*)d_in[2], (const float*)d_in[3],
        (const float*)d_in[4], (const float*)d_in[5], ew);

    attn2<<<2 * NWIN, 256, 0, stream>>>(ew, wq_e, bq_e,
        (const float*)d_in[14], wg_e,
        (const float*)d_in[11], (const float*)d_in[13], sige, oute);

    proj_ln2<<<2 * MROWS / 64, 256, 0, stream>>>(oute, outb, sige, wp_e,
        (const float*)d_in[16], (const float*)d_in[18], e_f, b_f,
        (const float*)d_in[19], (const float*)d_in[20],
        (const float*)d_in[21], (const float*)d_in[22], xe, lne);

    mlp3<<<2 * MROWS / 64, 256, 0, stream>>>(lne, w1_e,
        (const float*)d_in[24], (const float*)d_in[28], w2_e,
        (const float*)d_in[26], (const float*)d_in[30], xe);
}

// Round 15
// 705.462 us; speedup vs baseline: 1.1430x; 1.0096x over previous
//
#include <hip/hip_runtime.h>
#include <hip/hip_bf16.h>

typedef unsigned short u16;
typedef unsigned int u32;
typedef __attribute__((ext_vector_type(8))) short s16x8;
typedef __attribute__((ext_vector_type(4))) float f32x4;

constexpr int CD    = 180;
constexpr int CP    = 192;              // K-padded channel count
constexpr int BATCH = 4;
constexpr int RES   = 128;
constexpr int LSZ   = RES * RES;        // 16384
constexpr int NHEAD = 6;
constexpr int DH    = 30;
constexpr int NTOK  = 64;
constexpr int NWIN  = 1024;
constexpr int MROWS = NWIN * NTOK;      // 65536
constexpr size_t S192 = (size_t)MROWS * CP;
constexpr size_t S180 = (size_t)MROWS * CD;
constexpr size_t XSZ  = (size_t)BATCH * CD * LSZ;

__device__ __forceinline__ float b2f(u16 u) { return __uint_as_float(((u32)u) << 16); }
__device__ __forceinline__ u16 f2b(float f) {
    __hip_bfloat16 h = __float2bfloat16(f);
    return *reinterpret_cast<u16*>(&h);
}
// fast GELU (tanh form); |err vs exact erf-GELU| <~1e-3
__device__ __forceinline__ float gelu_f(float x) {
    float y = 0.7978845608028654f * (x + 0.044715f * x * x * x);
    float t = __expf(-2.f * fabsf(y));
    float th = (1.f - t) / (1.f + t);
    th = copysignf(th, y);
    return 0.5f * x * (1.f + th);
}

// ---------------- merged weight prep: 8 fragment-major jobs in one launch
struct PrepArgs {
    const float *s0, *s1, *s2, *s3, *s4, *s5, *s6, *s7;
    u16* dst;   // base of contiguous dst region (wg_e)
};
__device__ __forceinline__ void do_frag(const float* __restrict__ src,
        u16* __restrict__ dst, int N, int K, int nks, int li) {
    int e = li & 7, lr = (li >> 3) & 15, lk = (li >> 7) & 3, rest = li >> 9;
    int ks = rest % nks, ct = rest / nks;
    int n = ct * 16 + lr, k = ks * 32 + lk * 8 + e;
    float v = (n < N && k < K) ? src[n * K + k] : 0.f;
    dst[li] = f2b(v);
}
// proj weights: K=384 split layout (oute cols 0-191 pad, outb 192-383 pad)
__device__ __forceinline__ void do_frag_proj(const float* __restrict__ src,
        u16* __restrict__ dst, int li) {
    int e = li & 7, lr = (li >> 3) & 15, lk = (li >> 7) & 3, rest = li >> 9;
    int ks = rest % 12, ct = rest / 12;
    int n = ct * 16 + lr, k = ks * 32 + lk * 8 + e;
    int khalf = k & 191;
    int ksrc = (k < 192) ? khalf : 180 + khalf;
    float v = (n < 180 && khalf < 180) ? src[n * 360 + ksrc] : 0.f;
    dst[li] = f2b(v);
}
__global__ __launch_bounds__(256) void prep_all(PrepArgs pa) {
    int bid = blockIdx.x, t = threadIdx.x;
    if (bid < 144)       do_frag(pa.s0, pa.dst,          180, 180,  6, (bid       ) * 256 + t);
    else if (bid < 288)  do_frag(pa.s1, pa.dst + 36864,  180, 180,  6, (bid - 144 ) * 256 + t);
    else if (bid < 576)  do_frag_proj(pa.s2, pa.dst + 73728,           (bid - 288 ) * 256 + t);
    else if (bid < 864)  do_frag_proj(pa.s3, pa.dst + 147456,          (bid - 576 ) * 256 + t);
    else if (bid < 1440) do_frag(pa.s4, pa.dst + 221184, 720, 180,  6, (bid - 864 ) * 256 + t);
    else if (bid < 2016) do_frag(pa.s5, pa.dst + 368640, 720, 180,  6, (bid - 1440) * 256 + t);
    else if (bid < 2592) do_frag(pa.s6, pa.dst + 516096, 180, 720, 24, (bid - 2016) * 256 + t);
    else                 do_frag(pa.s7, pa.dst + 663552, 180, 720, 24, (bid - 2592) * 256 + t);
}

// ---------------- merged qkv weight prep (e and b)
__global__ __launch_bounds__(256) void prep_wqkv2(
        const float* __restrict__ we, const float* __restrict__ be,
        const float* __restrict__ wb, const float* __restrict__ bb,
        u16* __restrict__ wp_base, float* __restrict__ bp_base) {
    int gi = blockIdx.x * 256 + threadIdx.x;
    int flag = gi >= 576 * 192;
    int i = flag ? gi - 576 * 192 : gi;
    if (i >= 576 * 192) return;
    const float* w = flag ? wb : we;
    const float* bsrc = flag ? bb : be;
    u16* wp = wp_base + (size_t)flag * (576 * 192);
    float* bp = bp_base + flag * 576;
    int e = i & 7, lr = (i >> 3) & 15, lk = (i >> 7) & 3, rest = i >> 9;
    int ks = rest % 6, rest2 = rest / 6;
    int ct = rest2 % 6, head = rest2 / 6;
    int rr = ct * 16 + lr;
    int sec = rr >> 5, dd = rr & 31;
    int srow = sec * 180 + head * 30 + dd;
    int k = ks * 32 + lk * 8 + e;
    float scale = (sec == 0) ? 0.18257418583505536f : 1.f;
    float v = (dd < 30 && k < 180) ? w[srow * 180 + k] * scale : 0.f;
    wp[i] = f2b(v);
    if (ks == 0 && lk == 0 && e == 0)
        bp[head * 96 + rr] = (dd < 30) ? bsrc[srow] * scale : 0.f;
}

// ---------------- merged LN1 + roll + window partition (e and b)
__global__ __launch_bounds__(256) void ln_win2(
    const float* __restrict__ e_f, const float* __restrict__ b_f,
    const float* __restrict__ g_e, const float* __restrict__ be_e,
    const float* __restrict__ g_b, const float* __restrict__ be_b,
    u16* __restrict__ dst_base) {
    __shared__ float tile[NTOK][CD + 1];
    int bid = blockIdx.x;
    int flag = bid >> 10;
    int widx = bid & 1023;
    const float* src = flag ? b_f : e_f;
    const float* gamma = flag ? g_b : g_e;
    const float* beta = flag ? be_b : be_e;
    u16* dst = dst_base + (size_t)flag * S192;
    int b = widx >> 8, wrem = widx & 255;
    int wh = wrem >> 4, ww = wrem & 15;
    int t = threadIdx.x;
    for (int i = t; i < NTOK * CD; i += 256) {
        int c = i >> 6, pos = i & 63;
        int sh = ((wh << 3) + (pos >> 3) + 4) & 127;
        int sw = ((ww << 3) + (pos & 7) + 4) & 127;
        tile[pos][c] = src[(((size_t)b * CD + c) << 14) + (sh << 7) + sw];
    }
    __syncthreads();
    int pos = t >> 2, sub = t & 3;
    float s = 0.f, ss = 0.f;
    for (int k = 0; k < 45; ++k) {
        float v = tile[pos][sub * 45 + k];
        s += v; ss += v * v;
    }
    s += __shfl_xor(s, 1); ss += __shfl_xor(ss, 1);
    s += __shfl_xor(s, 2); ss += __shfl_xor(ss, 2);
    float mean = s * (1.f / CD);
    float rstd = rsqrtf(ss * (1.f / CD) - mean * mean + 1e-5f);
    size_t obase = ((size_t)widx * NTOK + pos) * CP;
    for (int k = 0; k < 45; ++k) {
        int c = sub * 45 + k;
        dst[obase + c] = f2b((tile[pos][c] - mean) * rstd * gamma[c] + beta[c]);
    }
    if (sub == 3) {
        for (int k = 0; k < 12; ++k) dst[obase + CD + k] = 0;
    }
}

// ---------------- merged MFMA attention (e and b) + fused sigmoid gate
__global__ __launch_bounds__(256) void attn2(
    const u16* __restrict__ ew_base, const u16* __restrict__ wq_base,
    const float* __restrict__ bq_base, const float* __restrict__ rpb,
    const u16* __restrict__ wg_base, const float* __restrict__ gbias_e,
    const float* __restrict__ gbias_b, u16* __restrict__ sig_base,
    u16* __restrict__ out_base) {
    __shared__ __align__(16) char smem[28448];
    u16*   ews  = (u16*)smem;                 // 64*200*2 = 25600 B (staging, dies)
    u16*   Qs   = (u16*)smem;                 // 64*36*2  =  4608
    u16*   Ks   = (u16*)(smem + 4608);
    u16*   Vt   = (u16*)(smem + 9216);        // 32*72*2  =  4608
    u16*   Pb   = (u16*)(smem + 13824);       // 64*72*2  =  9216
    float* rpbs = (float*)(smem + 23040);     // 1350*4   =  5400

    int bid = blockIdx.x;
    int flag = bid >> 10;
    int widx = bid & 1023;
    const u16* ew = ew_base + (size_t)flag * S192;
    const u16* Wq = wq_base + (size_t)flag * (576 * 192);
    const float* Bq = bq_base + flag * 576;
    u16* outp = out_base + (size_t)flag * S180;

    int wrem = widx & 255;
    int wh = wrem >> 4, ww = wrem & 15;
    bool edge = (wh == 15) || (ww == 15);
    int t = threadIdx.x;
    size_t wbase = (size_t)widx * NTOK * CD;
    size_t wb192 = (size_t)widx * NTOK * CP;

    for (int i = t; i < 64 * 24; i += 256) {
        int row = i / 24, seg = i % 24;
        *(s16x8*)&ews[row * 200 + seg * 8] = *(const s16x8*)&ew[wb192 + (size_t)row * CP + seg * 8];
    }
    __syncthreads();

    int wave = t >> 6, lane = t & 63, lr = lane & 15, lk = lane >> 4;
    s16x8 a[6];
    #pragma unroll
    for (int ks = 0; ks < 6; ++ks)
        a[ks] = *(const s16x8*)&ews[(wave * 16 + lr) * 200 + ks * 32 + lk * 8];
    __syncthreads();   // all waves done reading ews; region reusable

    for (int i = t; i < 1350; i += 256) rpbs[i] = rpb[i];  // visible after next barrier

    // ---- fused gate: sig = sigmoid(ew @ Wg^T + gbias), register/global only
    {
        const u16* Wg = wg_base + flag * 36864;
        const float* gbias = flag ? gbias_b : gbias_e;
        u16* sig = sig_base + (size_t)flag * S192;
        for (int ct = 0; ct < 12; ++ct) {
            f32x4 acc = {0.f, 0.f, 0.f, 0.f};
            #pragma unroll
            for (int ks = 0; ks < 6; ++ks) {
                s16x8 b = *(const s16x8*)&Wg[((size_t)(ct * 6 + ks) * 64 + lane) * 8];
                acc = __builtin_amdgcn_mfma_f32_16x16x32_bf16(a[ks], b, acc, 0, 0, 0);
            }
            int c = ct * 16 + lr;
            if (c < CD) {
                float bb = gbias[c];
                #pragma unroll
                for (int j = 0; j < 4; ++j) {
                    int rowm = widx * 64 + wave * 16 + lk * 4 + j;
                    float v = acc[j] + bb;
                    v = 1.f / (1.f + __expf(-v));
                    sig[(size_t)rowm * CP + c] = f2b(v);
                }
            }
        }
    }

    for (int h = 0; h < NHEAD; ++h) {
        #pragma unroll
        for (int ct = 0; ct < 6; ++ct) {
            f32x4 acc = {0.f, 0.f, 0.f, 0.f};
            #pragma unroll
            for (int ks = 0; ks < 6; ++ks) {
                s16x8 b = *(const s16x8*)&Wq[(((size_t)(h * 6 + ct) * 6 + ks) * 64 + lane) * 8];
                acc = __builtin_amdgcn_mfma_f32_16x16x32_bf16(a[ks], b, acc, 0, 0, 0);
            }
            int sec = ct >> 1;
            int dd = ((ct & 1) << 4) + lr;
            float bb = Bq[h * 96 + ct * 16 + lr];
            #pragma unroll
            for (int j = 0; j < 4; ++j) {
                int tok = wave * 16 + lk * 4 + j;
                float v = acc[j] + bb;
                if (sec == 0)      Qs[tok * 36 + dd] = f2b(v);
                else if (sec == 1) Ks[tok * 36 + dd] = f2b(v);
                else               Vt[dd * 72 + tok] = f2b(v);
            }
        }
        __syncthreads();
        f32x4 sv[4];
        {
            s16x8 qa = *(const s16x8*)&Qs[(wave * 16 + lr) * 36 + lk * 8];
            #pragma unroll
            for (int ct = 0; ct < 4; ++ct) {
                s16x8 kb = *(const s16x8*)&Ks[(ct * 16 + lr) * 36 + lk * 8];
                f32x4 z = {0.f, 0.f, 0.f, 0.f};
                sv[ct] = __builtin_amdgcn_mfma_f32_16x16x32_bf16(qa, kb, z, 0, 0, 0);
            }
            #pragma unroll
            for (int ct = 0; ct < 4; ++ct) {
                int sj = ct * 16 + lr;
                int jh = sj >> 3, jw = sj & 7;
                #pragma unroll
                for (int j = 0; j < 4; ++j) {
                    int si = wave * 16 + lk * 4 + j;
                    int ih = si >> 3, iw = si & 7;
                    float v = sv[ct][j] + rpbs[((ih - jh + 7) * 15 + (iw - jw + 7)) * 6 + h];
                    if (edge) {
                        int hri = (wh << 3) + ih, wri = (ww << 3) + iw;
                        int hrj = (wh << 3) + jh, wrj = (ww << 3) + jw;
                        int ri = (hri < 120 ? 0 : (hri < 124 ? 1 : 2)) * 3 + (wri < 120 ? 0 : (wri < 124 ? 1 : 2));
                        int rj = (hrj < 120 ? 0 : (hrj < 124 ? 1 : 2)) * 3 + (wrj < 120 ? 0 : (wrj < 124 ? 1 : 2));
                        if (ri != rj) v -= 100.f;
                    }
                    sv[ct][j] = v;
                }
            }
        }
        __syncthreads();
        #pragma unroll
        for (int j = 0; j < 4; ++j) {
            float mx = fmaxf(fmaxf(sv[0][j], sv[1][j]), fmaxf(sv[2][j], sv[3][j]));
            mx = fmaxf(mx, __shfl_xor(mx, 1));
            mx = fmaxf(mx, __shfl_xor(mx, 2));
            mx = fmaxf(mx, __shfl_xor(mx, 4));
            mx = fmaxf(mx, __shfl_xor(mx, 8));
            float e0 = __expf(sv[0][j] - mx);
            float e1 = __expf(sv[1][j] - mx);
            float e2 = __expf(sv[2][j] - mx);
            float e3 = __expf(sv[3][j] - mx);
            float sm = e0 + e1 + e2 + e3;
            sm += __shfl_xor(sm, 1);
            sm += __shfl_xor(sm, 2);
            sm += __shfl_xor(sm, 4);
            sm += __shfl_xor(sm, 8);
            float inv = 1.f / sm;
            int row = wave * 16 + lk * 4 + j;
            Pb[row * 72 +      lr] = f2b(e0 * inv);
            Pb[row * 72 + 16 + lr] = f2b(e1 * inv);
            Pb[row * 72 + 32 + lr] = f2b(e2 * inv);
            Pb[row * 72 + 48 + lr] = f2b(e3 * inv);
        }
        __syncthreads();
        {
            s16x8 pa0 = *(const s16x8*)&Pb[(wave * 16 + lr) * 72 + lk * 8];
            s16x8 pa1 = *(const s16x8*)&Pb[(wave * 16 + lr) * 72 + 32 + lk * 8];
            #pragma unroll
            for (int ct = 0; ct < 2; ++ct) {
                f32x4 acc = {0.f, 0.f, 0.f, 0.f};
                s16x8 vb0 = *(const s16x8*)&Vt[(ct * 16 + lr) * 72 + lk * 8];
                s16x8 vb1 = *(const s16x8*)&Vt[(ct * 16 + lr) * 72 + 32 + lk * 8];
                acc = __builtin_amdgcn_mfma_f32_16x16x32_bf16(pa0, vb0, acc, 0, 0, 0);
                acc = __builtin_amdgcn_mfma_f32_16x16x32_bf16(pa1, vb1, acc, 0, 0, 0);
                int dd = ct * 16 + lr;
                if (dd < DH) {
                    #pragma unroll
                    for (int j = 0; j < 4; ++j) {
                        int tok = wave * 16 + lk * 4 + j;
                        outp[wbase + (size_t)tok * CD + h * DH + dd] = f2b(acc[j]);
                    }
                }
            }
        }
        __syncthreads();
    }
}

// ---------------- FUSED proj + addback + LN2 + MLP (one block = 64 windowed rows)
// Phase A: proj GEMM (K=384 split) + residual + LN2 -> Xs LDS (fragment-major)
// Phase B: MLP v6 body (GEMM1+GELU -> Hid, GEMM2 -> xout RMW)
__global__ __launch_bounds__(256) void proj_mlp(
    const u16* __restrict__ oute, const u16* __restrict__ outb,
    const u16* __restrict__ sig_base, const u16* __restrict__ wp_base,
    const float* __restrict__ bias_e, const float* __restrict__ bias_b,
    const float* __restrict__ e_f, const float* __restrict__ b_f,
    const float* __restrict__ g2e, const float* __restrict__ be2e,
    const float* __restrict__ g2b, const float* __restrict__ be2b,
    const u16* __restrict__ w1_base, const float* __restrict__ b1_e,
    const float* __restrict__ b1_b, const u16* __restrict__ w2_base,
    const float* __restrict__ b2_e, const float* __restrict__ b2_b,
    float* __restrict__ xout_base) {
    __shared__ __align__(16) u16 Xs[6 * 4 * 64 * 8];    // 24576 B
    __shared__ __align__(16) u16 Hid[4 * 4 * 64 * 8];   // 16384 B  (total 40960)
    int bid = blockIdx.x, t = threadIdx.x;
    int flag = bid >> 10;
    int rb = bid & 1023;
    const u16* sig = sig_base + (size_t)flag * S192;
    const u16* Wb = wp_base + flag * (192 * 384);
    const float* bias = flag ? bias_b : bias_e;
    const float* src = flag ? b_f : e_f;
    const float* gamma = flag ? g2b : g2e;
    const float* beta2 = flag ? be2b : be2e;
    const u16* W1p = w1_base + (size_t)flag * (768 * 192);
    const u16* W2p = w2_base + (size_t)flag * (192 * 768);
    const float* b1 = flag ? b1_b : b1_e;
    const float* b2v = flag ? b2_b : b2_e;
    float* xout = xout_base + (size_t)flag * XSZ;
    size_t rb64 = (size_t)rb * 64;
    int wave = t >> 6, lane = t & 63, lr = lane & 15, lk = lane >> 4;
    int row = wave * 16 + lr;

    // ======== Phase A: proj + residual + LN2 ========
    const u16* oe_row = oute + (rb64 + row) * (size_t)CD;
    const u16* ob_row = outb + (rb64 + row) * (size_t)CD;
    const u16* sg_row = sig + (rb64 + row) * (size_t)CP;
    {
        s16x8 a[12];
        #pragma unroll
        for (int ks = 0; ks < 12; ++ks) {
            int koff = (ks >= 6 ? ks - 6 : ks) * 32 + lk * 8;   // 0..184
            const u16* sp = (ks < 6) ? oe_row : ob_row;
            s16x8 v = *(const s16x8*)&sp[koff];
            s16x8 g = *(const s16x8*)&sg_row[koff];
            s16x8 r;
            #pragma unroll
            for (int e = 0; e < 8; ++e) {
                float p = b2f((u16)v[e]) * b2f((u16)g[e]);
                if ((ks == 5 || ks == 11) && (koff + e >= 180)) p = 0.f;
                r[e] = (short)f2b(p);
            }
            a[ks] = r;
        }

        int rowm0 = (int)rb64 + wave * 16 + lk * 4;
        int win = rowm0 >> 6, pos0 = rowm0 & 63;
        int bb_ = win >> 8, whh = (win >> 4) & 15, www = win & 15;
        int hh = (((whh << 3) + (pos0 >> 3)) + 4) & 127;
        int w20 = (((www << 3) + (pos0 & 7)) + 4) & 127;
        size_t sbase = (((size_t)bb_ * CD) << 14) + (hh << 7) + w20;

        f32x4 val[12];
        float s0 = 0.f, s1 = 0.f, s2 = 0.f, s3 = 0.f;
        float q0 = 0.f, q1 = 0.f, q2 = 0.f, q3 = 0.f;
        #pragma unroll
        for (int ct = 0; ct < 12; ++ct) {
            f32x4 acc = {0.f, 0.f, 0.f, 0.f};
            #pragma unroll
            for (int ks = 0; ks < 12; ++ks) {
                s16x8 b = *(const s16x8*)&Wb[((size_t)(ct * 12 + ks) * 64 + lane) * 8];
                acc = __builtin_amdgcn_mfma_f32_16x16x32_bf16(a[ks], b, acc, 0, 0, 0);
            }
            int c = ct * 16 + lr;
            if (c < CD) {
                float bv = bias[c];
                size_t idx0 = sbase + ((size_t)c << 14);
                float4 s4 = *(const float4*)&src[idx0];
                f32x4 x;
                x[0] = s4.x + acc[0] + bv;
                x[1] = s4.y + acc[1] + bv;
                x[2] = s4.z + acc[2] + bv;
                x[3] = s4.w + acc[3] + bv;
                *(float4*)&xout[idx0] = make_float4(x[0], x[1], x[2], x[3]);
                val[ct] = x;
                s0 += x[0]; q0 += x[0] * x[0];
                s1 += x[1]; q1 += x[1] * x[1];
                s2 += x[2]; q2 += x[2] * x[2];
                s3 += x[3]; q3 += x[3] * x[3];
            } else {
                val[ct] = (f32x4){0.f, 0.f, 0.f, 0.f};
            }
        }
        #pragma unroll
        for (int m = 1; m < 16; m <<= 1) {
            s0 += __shfl_xor(s0, m); q0 += __shfl_xor(q0, m);
            s1 += __shfl_xor(s1, m); q1 += __shfl_xor(q1, m);
            s2 += __shfl_xor(s2, m); q2 += __shfl_xor(q2, m);
            s3 += __shfl_xor(s3, m); q3 += __shfl_xor(q3, m);
        }
        float mean[4], rstd[4];
        mean[0] = s0 * (1.f / CD); rstd[0] = rsqrtf(q0 * (1.f / CD) - mean[0] * mean[0] + 1e-5f);
        mean[1] = s1 * (1.f / CD); rstd[1] = rsqrtf(q1 * (1.f / CD) - mean[1] * mean[1] + 1e-5f);
        mean[2] = s2 * (1.f / CD); rstd[2] = rsqrtf(q2 * (1.f / CD) - mean[2] * mean[2] + 1e-5f);
        mean[3] = s3 * (1.f / CD); rstd[3] = rsqrtf(q3 * (1.f / CD) - mean[3] * mean[3] + 1e-5f);
        // write normalized bf16 directly into Xs (fragment-major):
        // element (row=wave*16+lk*4+j, col=c): sm=wave, slr=lk*4+j,
        // sks=c>>5, slk=(c>>3)&3, e=c&7. Covers all 64x192 exactly once (pad=0).
        #pragma unroll
        for (int ct = 0; ct < 12; ++ct) {
            int c = ct * 16 + lr;
            float g = 0.f, be = 0.f;
            if (c < CD) { g = gamma[c]; be = beta2[c]; }
            int sks = c >> 5, slk = (c >> 3) & 3, e = c & 7;
            #pragma unroll
            for (int j = 0; j < 4; ++j) {
                u16 o = 0;
                if (c < CD) o = f2b((val[ct][j] - mean[j]) * rstd[j] * g + be);
                Xs[(((sks * 4 + wave) * 64) + (slk * 16 + lk * 4 + j)) * 8 + e] = o;
            }
        }
    }
    __syncthreads();

    // ======== Phase B: MLP (proven v6 body) ========
    f32x4 acc2[3][4];
    #pragma unroll
    for (int c = 0; c < 3; ++c)
        #pragma unroll
        for (int m = 0; m < 4; ++m) acc2[c][m] = (f32x4){0.f, 0.f, 0.f, 0.f};

    for (int ch = 0; ch < 6; ++ch) {
        int ctg0 = ch * 8 + wave * 2, ctg1 = ctg0 + 1;
        f32x4 h0[4], h1[4];
        #pragma unroll
        for (int m = 0; m < 4; ++m) { h0[m] = (f32x4){0,0,0,0}; h1[m] = (f32x4){0,0,0,0}; }
        #pragma unroll
        for (int ks = 0; ks < 6; ++ks) {
            s16x8 b0 = *(const s16x8*)&W1p[((size_t)(ctg0 * 6 + ks) * 64 + lane) * 8];
            s16x8 b1v = *(const s16x8*)&W1p[((size_t)(ctg1 * 6 + ks) * 64 + lane) * 8];
            #pragma unroll
            for (int m = 0; m < 4; ++m) {
                s16x8 av = *(const s16x8*)&Xs[((ks * 4 + m) * 64 + lane) * 8];  // conflict-free
                h0[m] = __builtin_amdgcn_mfma_f32_16x16x32_bf16(av, b0, h0[m], 0, 0, 0);
                h1[m] = __builtin_amdgcn_mfma_f32_16x16x32_bf16(av, b1v, h1[m], 0, 0, 0);
            }
        }
        #pragma unroll 2
        for (int cti = 0; cti < 2; ++cti) {
            int hcol = (ctg0 + cti) * 16 + lr;
            float bb = (hcol < 720) ? b1[hcol] : 0.f;
            int lcol = wave * 32 + cti * 16 + lr;        // chunk-local col 0..127
            int ksr = lcol >> 5, lkr = (lcol >> 3) & 3, er = lcol & 7;
            #pragma unroll
            for (int m = 0; m < 4; ++m) {
                f32x4 hv = cti ? h1[m] : h0[m];
                #pragma unroll
                for (int j = 0; j < 4; ++j) {
                    float v = gelu_f(hv[j] + bb);
                    Hid[(((ksr * 4 + m) * 64) + (lkr * 16 + lk * 4 + j)) * 8 + er] = f2b(v);
                }
            }
        }
        __syncthreads();
        #pragma unroll
        for (int ks = 0; ks < 4; ++ks) {
            int gks = ch * 4 + ks;
            s16x8 av[4];
            #pragma unroll
            for (int m = 0; m < 4; ++m)
                av[m] = *(const s16x8*)&Hid[((ks * 4 + m) * 64 + lane) * 8];    // conflict-free
            #pragma unroll
            for (int ct3 = 0; ct3 < 3; ++ct3) {
                int ctg = wave * 3 + ct3;
                s16x8 b = *(const s16x8*)&W2p[((size_t)(ctg * 24 + gks) * 64 + lane) * 8];
                #pragma unroll
                for (int m = 0; m < 4; ++m)
                    acc2[ct3][m] = __builtin_amdgcn_mfma_f32_16x16x32_bf16(av[m], b, acc2[ct3][m], 0, 0, 0);
            }
        }
        __syncthreads();
    }
    // epilogue: float4 RMW into xout (NCHW); windowed row -> spatial
    #pragma unroll
    for (int m = 0; m < 4; ++m) {
        int mm0 = rb * 64 + m * 16 + lk * 4;
        int win = mm0 >> 6, pos0 = mm0 & 63;
        int b = win >> 8, whh = (win >> 4) & 15, www = win & 15;
        int hh = (((whh << 3) + (pos0 >> 3)) + 4) & 127;
        int w20 = (((www << 3) + (pos0 & 7)) + 4) & 127;
        size_t sbase = (((size_t)b * CD) << 14) + (hh << 7) + w20;
        #pragma unroll
        for (int ct3 = 0; ct3 < 3; ++ct3) {
            int cc = (wave * 3 + ct3) * 16 + lr;
            if (cc < CD) {
                float bb = b2v[cc];
                size_t idx0 = sbase + ((size_t)cc << 14);
                float4 o4 = *(const float4*)&xout[idx0];
                o4.x += acc2[ct3][m][0] + bb;
                o4.y += acc2[ct3][m][1] + bb;
                o4.z += acc2[ct3][m][2] + bb;
                o4.w += acc2[ct3][m][3] + bb;
                *(float4*)&xout[idx0] = o4;
            }
        }
    }
}

extern "C" void kernel_launch(void* const* d_in, const int* in_sizes, int n_in,
                              void* d_out, int out_size, void* d_ws, size_t ws_size,
                              hipStream_t stream) {
    const float* e_f = (const float*)d_in[0];
    const float* b_f = (const float*)d_in[1];

    u16* ew   = (u16*)d_ws;
    u16* bw   = ew + S192;
    u16* sige = bw + S192;
    u16* sigb = sige + S192;
    u16* oute = sigb + S192;
    u16* outb = oute + S180;
    u16* wg_e = outb + S180;                 // contiguous prep region
    u16* wp_e = wg_e + 2 * 36864;
    u16* w1_e = wp_e + 2 * 73728;
    u16* w2_e = w1_e + 2 * 147456;
    u16* wq_e = w2_e + 2 * 147456;           // 2 * 576*192
    float* bq_e = (float*)(wq_e + 2 * 576 * 192);   // 2 * 576

    float* xe = (float*)d_out;

    PrepArgs pa;
    pa.s0 = (const float*)d_in[10];
    pa.s1 = (const float*)d_in[12];
    pa.s2 = (const float*)d_in[15];
    pa.s3 = (const float*)d_in[17];
    pa.s4 = (const float*)d_in[23];
    pa.s5 = (const float*)d_in[27];
    pa.s6 = (const float*)d_in[25];
    pa.s7 = (const float*)d_in[29];
    pa.dst = wg_e;
    prep_all<<<3168, 256, 0, stream>>>(pa);
    prep_wqkv2<<<(2 * 576 * 192 + 255) / 256, 256, 0, stream>>>(
        (const float*)d_in[6], (const float*)d_in[7],
        (const float*)d_in[8], (const float*)d_in[9], wq_e, bq_e);

    ln_win2<<<2 * NWIN, 256, 0, stream>>>(e_f, b_f,
        (const float*)d_in[2], (const float*)d_in[3],
        (const float*)d_in[4], (const float*)d_in[5], ew);

    attn2<<<2 * NWIN, 256, 0, stream>>>(ew, wq_e, bq_e,
        (const float*)d_in[14], wg_e,
        (const float*)d_in[11], (const float*)d_in[13], sige, oute);

    proj_mlp<<<2 * MROWS / 64, 256, 0, stream>>>(oute, outb, sige, wp_e,
        (const float*)d_in[16], (const float*)d_in[18], e_f, b_f,
        (const float*)d_in[19], (const float*)d_in[20],
        (const float*)d_in[21], (const float*)d_in[22],
        w1_e, (const float*)d_in[24], (const float*)d_in[28],
        w2_e, (const float*)d_in[26], (const float*)d_in[30], xe);
}